// Round 16
// baseline (53.793 us; speedup 1.0000x reference)
//
#include <hip/hip_runtime.h>

typedef __attribute__((ext_vector_type(8))) short short8;
typedef __attribute__((ext_vector_type(8))) unsigned short ushort8;
typedef __attribute__((ext_vector_type(4))) float f32x4;

// Problem constants
constexpr int B_ = 8, IN_C_ = 64, IN_L_ = 64, T_ = 256, OUT_C_ = 64, OUT_L_ = 64;
constexpr float EPS_ = 1e-5f;

// xT_pad: bf16 [8 b][66 lp][258 tp][64 ic]; lp = l+1, tp = t+1, halo rows/cols = 0
constexpr int XT_LP = 66, XT_TP = 258, XT_IC = 64;
constexpr int XT_LSTRIDE = XT_TP * XT_IC;            // 16512 elems
constexpr int XT_BSTRIDE = XT_LP * XT_LSTRIDE;       // 1,089,792 elems
constexpr size_t XT_ELEMS = (size_t)B_ * XT_BSTRIDE; // 8,718,336
constexpr size_t XT_BYTES = XT_ELEMS * 2;            // 17,436,672
// wT2: bf16 [64 l][9 tap][64 c][64 ic]
constexpr size_t WT2_ELEMS = 64ull * 9 * 64 * 64;    // 2,359,296
constexpr size_t WT2_OFF_B = XT_BYTES;
constexpr size_t PART_OFF_B = WT2_OFF_B + WT2_ELEMS * 2;   // 22,155,264
constexpr size_t PART_BYTES = 512ull * 128 * 4;            // 256 KB
constexpr size_t TMP_OFF_B = PART_OFF_B + PART_BYTES;      // 22,417,408
constexpr size_t TMP_BYTES = (size_t)B_ * OUT_C_ * OUT_L_ * T_ * 2;
constexpr size_t WS_NEED = TMP_OFF_B;                      // fp32 fallback
constexpr size_t WS_NEED2 = TMP_OFF_B + TMP_BYTES;         // 39,194,624

__device__ __forceinline__ unsigned short f2bf(float f) {
  unsigned u = __float_as_uint(f);
  return (unsigned short)((u + 0x7fffu + ((u >> 16) & 1u)) >> 16);
}

__device__ __forceinline__ void gload_lds16(const void* g, void* l) {
  __builtin_amdgcn_global_load_lds(
      (const __attribute__((address_space(1))) unsigned int*)g,
      (__attribute__((address_space(3))) unsigned int*)l, 16, 0, 0);
}

// ---------------------------------------------------------------------------
// Prep (r12, unchanged): blocks [0,144) coalesced wprep transpose;
// [144,1168) xprep LDS transpose; [1168,1176) xT halo zero.
// ---------------------------------------------------------------------------
__global__ __launch_bounds__(256) void prep_kernel(const float* __restrict__ x,
                                                   const float* __restrict__ w,
                                                   unsigned short* __restrict__ xT,
                                                   unsigned short* __restrict__ wT2) {
  const int bid = blockIdx.x;
  const int tid = threadIdx.x;
  __shared__ unsigned char shmem[34816];
  if (bid < 144) {
    const int tap = bid >> 4;
    const int c0 = (bid & 15) * 4;
    auto wls = (unsigned short(*)[4][68])shmem;  // [l][cl][ic] (pad 68)
    {
      const int ic = tid >> 2, cl = tid & 3;
      const float* src = w + (((size_t)(ic * 9 + tap) * 64) + (c0 + cl)) * 64;
#pragma unroll
      for (int e = 0; e < 16; ++e) {
        float4 v = ((const float4*)src)[e];
        const int l = e * 4;
        wls[l + 0][cl][ic] = f2bf(v.x);
        wls[l + 1][cl][ic] = f2bf(v.y);
        wls[l + 2][cl][ic] = f2bf(v.z);
        wls[l + 3][cl][ic] = f2bf(v.w);
      }
    }
    __syncthreads();
    {
      const int l = tid >> 2, cl = tid & 3;
      const unsigned short* row = &wls[l][cl][0];
      uint4* dst = (uint4*)(wT2 + ((size_t)(l * 9 + tap)) * 4096 + (c0 + cl) * 64);
#pragma unroll
      for (int q = 0; q < 8; ++q) dst[q] = ((const uint4*)row)[q];
    }
  } else if (bid < 1168) {
    const int u = bid - 144;
    const int th = u & 1, l = (u >> 1) & 63, b = u >> 7;
    const int t0 = th * 128;
    auto ls = (unsigned short(*)[132])shmem;  // [ic][t-local]
    {
      const int ic = tid >> 2, q = tid & 3;
      const float4* src = (const float4*)(x + (((size_t)(b * 64 + ic) * 64 + l) * 256 + t0));
#pragma unroll
      for (int e = 0; e < 8; ++e) {
        float4 v = src[q * 8 + e];
        const int toff = (q * 8 + e) * 4;
        unsigned d0 = f2bf(v.x) | ((unsigned)f2bf(v.y) << 16);
        unsigned d1 = f2bf(v.z) | ((unsigned)f2bf(v.w) << 16);
        *(uint2*)&ls[ic][toff] = make_uint2(d0, d1);
      }
    }
    __syncthreads();
    {
      const int tl = tid >> 1, h = tid & 1;  // t-row, ic-half
      unsigned d[16];
#pragma unroll
      for (int k = 0; k < 16; ++k) {
        unsigned short a = ls[h * 32 + 2 * k][tl];
        unsigned short c = ls[h * 32 + 2 * k + 1][tl];
        d[k] = a | ((unsigned)c << 16);
      }
      unsigned short* dst =
          xT + ((size_t)(b * XT_LP + l + 1) * XT_TP + (t0 + tl + 1)) * XT_IC + h * 32;
      uint4* dv = (uint4*)dst;
      dv[0] = make_uint4(d[0], d[1], d[2], d[3]);
      dv[1] = make_uint4(d[4], d[5], d[6], d[7]);
      dv[2] = make_uint4(d[8], d[9], d[10], d[11]);
      dv[3] = make_uint4(d[12], d[13], d[14], d[15]);
    }
  } else {
    const int b = bid - 1168;  // 0..7
    unsigned short* base = xT + (size_t)b * XT_BSTRIDE;
    const short8 z = {};
    for (int ci = tid; ci < 5184; ci += 256) {
      size_t off;
      if (ci < 4128) {
        const int plane = ci / 2064, k = ci % 2064;
        off = (size_t)(plane ? 65 : 0) * XT_LSTRIDE + (size_t)k * 8;
      } else {
        const int k = ci - 4128;
        const int lp = k >> 4, rem = k & 15;
        const int tp = (rem < 8) ? 0 : 257;
        off = ((size_t)lp * XT_TP + tp) * 64 + (size_t)(rem & 7) * 8;
      }
      *(short8*)(base + off) = z;
    }
  }
}

// ---------------------------------------------------------------------------
// Main conv v6 (r15 + single-barrier-per-tap via B TRIPLE buffer): per (b,l)
// block, 256x64 GEMM, K=576 = 3 rows x 3 shifts x 64. A = one full padded xT
// row staged per i-row (unchanged). B = 3-deep LDS ring: per tap
// {vmcnt(N); s_barrier; BSTAGE(tap+2); compute(tap)}. Invariants (in-order
// vmcnt retirement, m135): at tap t, outstanding = STAGE(t) [oldest,2] +
// STAGE(t+1) [2] (+ 9 A-loads at j==0, youngest) -> vmcnt(2) drains my
// STAGE(t) before the common barrier (= publish); vmcnt(0) at j==0/tap 8 also
// drains the row-A loads. STAGE(t+2) overwrites buf[(t-1)%3] whose readers
// finished compute(t-1) before barrier(t). Barrier crossings 21 -> 11.
// Wave tile / swizzles / epilogue unchanged from r15.
// ---------------------------------------------------------------------------
__global__ __launch_bounds__(256, 2) void conv_mfma(
    const unsigned short* __restrict__ xT, const unsigned short* __restrict__ wT2,
    const float* __restrict__ bias, float* __restrict__ outf,
    unsigned short* __restrict__ tmpb, float* __restrict__ part) {
  const int orig = blockIdx.x;  // 0..511
  // l-major XCD swizzle: b = orig>>6, l = (orig&7)*8 + ((orig>>3)&7)
  const int wg = (orig >> 6) * 64 + (orig & 7) * 8 + ((orig >> 3) & 7);
  const int b = wg >> 6, l = wg & 63;
  const int tid = threadIdx.x;
  const int wid = tid >> 6, ln = tid & 63;
  const int lc = ln & 15, lg = ln >> 4;
  const int m0 = wid * 64;

  __shared__ unsigned short Arow[18432];   // 36 KB: one xT row (16512) + pad
  __shared__ unsigned short Bl[3][4096];   // 24 KB: B triple buffer (ring)

  // B source pre-swizzle: dst slot ln&7 of row-sub ln>>3 takes global slot
  // (ln&7)^(ln>>3)
  const int src_lane_off = ((ln >> 3) << 6) + ((((ln & 7) ^ (ln >> 3))) << 3);
  const unsigned short* wBase = wT2 + (size_t)l * 9 * 4096 + src_lane_off;
  const unsigned short* xRow0 = xT + (size_t)(b * XT_LP + l) * XT_LSTRIDE;

  // A row stage: 2304 chunks (2064 real + unguarded overrun pad; pad reads
  // land in later xT rows — in-bounds of ws, never consumed).
  auto ASTAGE = [&](int i) {
    const unsigned short* rb = xRow0 + (size_t)i * XT_LSTRIDE;
#pragma unroll
    for (int k = 0; k < 9; ++k) {
      const int cbase = k * 256 + wid * 64;  // wave-uniform
      const int ci = cbase + ln;
      const int tp = ci >> 3, s = ci & 7;
      gload_lds16(rb + tp * 64 + ((s ^ (tp & 7)) << 3), Arow + (size_t)cbase * 8);
    }
  };
  auto BSTAGE = [&](int buf, int tap) {
    const unsigned short* Bb = wBase + (size_t)tap * 4096;
#pragma unroll
    for (int q = 0; q < 2; ++q) {
      const int ch = wid * 2 + q;
      gload_lds16(Bb + ch * 512, &Bl[buf][0] + ch * 512);
    }
  };

  f32x4 acc[4][4] = {};

  ASTAGE(0);
  BSTAGE(0, 0);
  BSTAGE(1, 1);

#pragma unroll
  for (int tap = 0; tap < 9; ++tap) {
    const int i = tap / 3, j = tap - i * 3;  // compile-time (unrolled)
    // drain my STAGE(tap) (and row-A loads at j==0) but keep STAGE(tap+1)
    // in flight; then one common barrier publishes all waves' staging.
    if (tap == 8 || j == 0) {
      asm volatile("s_waitcnt vmcnt(0)" ::: "memory");
    } else {
      asm volatile("s_waitcnt vmcnt(2)" ::: "memory");
    }
    __builtin_amdgcn_sched_barrier(0);
    __builtin_amdgcn_s_barrier();
    __builtin_amdgcn_sched_barrier(0);
    if (tap + 2 < 9) BSTAGE((tap + 2) % 3, tap + 2);  // overwrites buf[(tap-1)%3]

    const unsigned short* Lb = &Bl[tap % 3][0];
#pragma unroll
    for (int kb = 0; kb < 2; ++kb) {
      const int q = kb * 4 + lg;
      short8 af[4], bf[4];
#pragma unroll
      for (int mi = 0; mi < 4; ++mi) {
        const int tp = m0 + mi * 16 + lc + j;  // column t+j, <= 257
        af[mi] = *(const short8*)(Arow + tp * 64 + ((q ^ (tp & 7)) << 3));
      }
#pragma unroll
      for (int ni = 0; ni < 4; ++ni)
        bf[ni] = *(const short8*)(Lb + (ni * 16 + lc) * 64 + ((q ^ (lc & 7)) << 3));
#pragma unroll
      for (int mi = 0; mi < 4; ++mi)
#pragma unroll
        for (int ni = 0; ni < 4; ++ni)
          acc[mi][ni] =
              __builtin_amdgcn_mfma_f32_16x16x32_bf16(af[mi], bf[ni], acc[mi][ni], 0, 0, 0);
    }

    if (j == 2 && i < 2) {
      __builtin_amdgcn_s_barrier();  // all waves done reading Arow(i)
      ASTAGE(i + 1);                 // drained by next tap's vmcnt(0)+barrier
    }
  }

  // epilogue: bias + store (bf16 or fp32) + fused stats.
  __syncthreads();
  float* sm = (float*)&Arow[0];  // sm[(wid*4+ni)*32 + lc*2 + sel]
#pragma unroll
  for (int ni = 0; ni < 4; ++ni) {
    const int c = ni * 16 + lc;
    const float bv = bias[c * 64 + l];
    float s = 0.f, s2 = 0.f;
    const size_t obase = ((size_t)(b * 64 + c) * 64 + l) * 256 + m0;
#pragma unroll
    for (int mi = 0; mi < 4; ++mi) {
      float vv[4];
#pragma unroll
      for (int r = 0; r < 4; ++r) {
        float v = acc[mi][ni][r] + bv;
        vv[r] = v;
        s += v;
        s2 += v * v;
      }
      if (tmpb) {
        unsigned d0 = f2bf(vv[0]) | ((unsigned)f2bf(vv[1]) << 16);
        unsigned d1 = f2bf(vv[2]) | ((unsigned)f2bf(vv[3]) << 16);
        *(uint2*)(tmpb + obase + mi * 16 + lg * 4) = make_uint2(d0, d1);
      } else {
        *(float4*)(outf + obase + mi * 16 + lg * 4) =
            make_float4(vv[0], vv[1], vv[2], vv[3]);
      }
    }
    s += __shfl_xor(s, 16);  s += __shfl_xor(s, 32);
    s2 += __shfl_xor(s2, 16); s2 += __shfl_xor(s2, 32);
    if (lg == 0) {
      sm[(wid * 4 + ni) * 32 + lc * 2] = s;
      sm[(wid * 4 + ni) * 32 + lc * 2 + 1] = s2;
    }
  }
  __syncthreads();
  if (tid < 128) {
    const int sel = tid >> 6, cc = tid & 63;
    const int ni = cc >> 4, lc2 = cc & 15;
    float r = 0.f;
#pragma unroll
    for (int w2 = 0; w2 < 4; ++w2) r += sm[(w2 * 4 + ni) * 32 + lc2 * 2 + sel];
    part[(size_t)wg * 128 + sel * 64 + cc] = r;
  }
}

// ---------------------------------------------------------------------------
// Merged stats + BN + PReLU (bf16 tmp -> fp32 out). Block = (c, seg):
// phase 1: redundantly reduce the 512x2 per-block partials for channel c;
// phase 2: apply BN+PReLU to a 1/32 slice of channel c.
// ---------------------------------------------------------------------------
__global__ __launch_bounds__(256) void bn_stats_prelu_b(
    const float* __restrict__ part, const float* __restrict__ gamma,
    const float* __restrict__ beta, const float* __restrict__ alpha,
    const unsigned short* __restrict__ tmp, float* __restrict__ out) {
  const int c = blockIdx.x >> 5;
  const int seg = blockIdx.x & 31;
  const int tid = threadIdx.x;
  float s = 0.f, s2 = 0.f;
  for (int i = tid; i < 512; i += 256) {
    s += part[(size_t)i * 128 + c];
    s2 += part[(size_t)i * 128 + 64 + c];
  }
#pragma unroll
  for (int off = 32; off; off >>= 1) {
    s += __shfl_down(s, off);
    s2 += __shfl_down(s2, off);
  }
  __shared__ float r0[4], r1[4];
  const int wid = tid >> 6, lane = tid & 63;
  if (lane == 0) { r0[wid] = s; r1[wid] = s2; }
  __syncthreads();
  const float S = r0[0] + r0[1] + r0[2] + r0[3];
  const float S2 = r1[0] + r1[1] + r1[2] + r1[3];
  const float inv_n = 1.0f / 131072.f;
  const float mean = S * inv_n;
  const float var = S2 * inv_n - mean * mean;
  const float sc = gamma[c] * rsqrtf(var + EPS_);
  const float sh = beta[c] - mean * sc;
  const float a = alpha[0];
  // slice: b = seg>>2, quarter = seg&3 ; per (b,c) plane = 2048 ushort8 chunks
  const size_t base8 = ((size_t)((seg >> 2) * 64 + c)) * 2048 + (size_t)(seg & 3) * 512;
#pragma unroll 2
  for (int k = tid; k < 512; k += 256) {
    const size_t i = base8 + k;
    ushort8 v = *(const ushort8*)(tmp + i * 8);
    float o[8];
#pragma unroll
    for (int r = 0; r < 8; ++r) {
      float f = __uint_as_float(((unsigned)v[r]) << 16) * sc + sh;
      o[r] = (f >= 0.f) ? f : a * f;
    }
    float4* op = (float4*)(out + i * 8);
    op[0] = make_float4(o[0], o[1], o[2], o[3]);
    op[1] = make_float4(o[4], o[5], o[6], o[7]);
  }
}

// fp32-in-place fallback variant (no tmp buffer).
__global__ __launch_bounds__(256) void bn_stats_prelu_f(
    const float* __restrict__ part, const float* __restrict__ gamma,
    const float* __restrict__ beta, const float* __restrict__ alpha,
    float* __restrict__ out) {
  const int c = blockIdx.x >> 5;
  const int seg = blockIdx.x & 31;
  const int tid = threadIdx.x;
  float s = 0.f, s2 = 0.f;
  for (int i = tid; i < 512; i += 256) {
    s += part[(size_t)i * 128 + c];
    s2 += part[(size_t)i * 128 + 64 + c];
  }
#pragma unroll
  for (int off = 32; off; off >>= 1) {
    s += __shfl_down(s, off);
    s2 += __shfl_down(s2, off);
  }
  __shared__ float r0[4], r1[4];
  const int wid = tid >> 6, lane = tid & 63;
  if (lane == 0) { r0[wid] = s; r1[wid] = s2; }
  __syncthreads();
  const float S = r0[0] + r0[1] + r0[2] + r0[3];
  const float S2 = r1[0] + r1[1] + r1[2] + r1[3];
  const float inv_n = 1.0f / 131072.f;
  const float mean = S * inv_n;
  const float var = S2 * inv_n - mean * mean;
  const float sc = gamma[c] * rsqrtf(var + EPS_);
  const float sh = beta[c] - mean * sc;
  const float a = alpha[0];
  const size_t base4 = ((size_t)((seg >> 2) * 64 + c)) * 4096 + (size_t)(seg & 3) * 1024;
  for (int k = tid; k < 1024; k += 256) {
    float4 v = ((float4*)out)[base4 + k];
    v.x = v.x * sc + sh; v.x = (v.x >= 0.f) ? v.x : a * v.x;
    v.y = v.y * sc + sh; v.y = (v.y >= 0.f) ? v.y : a * v.y;
    v.z = v.z * sc + sh; v.z = (v.z >= 0.f) ? v.z : a * v.z;
    v.w = v.w * sc + sh; v.w = (v.w >= 0.f) ? v.w : a * v.w;
    ((float4*)out)[base4 + k] = v;
  }
}

extern "C" void kernel_launch(void* const* d_in, const int* in_sizes, int n_in,
                              void* d_out, int out_size, void* d_ws, size_t ws_size,
                              hipStream_t stream) {
  const float* x = (const float*)d_in[0];
  const float* w = (const float*)d_in[1];
  const float* bias = (const float*)d_in[2];
  const float* gamma = (const float*)d_in[3];
  const float* beta = (const float*)d_in[4];
  const float* alpha = (const float*)d_in[5];
  float* out = (float*)d_out;

  unsigned short* xT = (unsigned short*)d_ws;
  unsigned short* wT2 = (unsigned short*)((char*)d_ws + WT2_OFF_B);
  float* part = (float*)((char*)d_ws + PART_OFF_B);

  if (ws_size >= WS_NEED2) {
    unsigned short* tmpb = (unsigned short*)((char*)d_ws + TMP_OFF_B);
    prep_kernel<<<dim3(1176), dim3(256), 0, stream>>>(x, w, xT, wT2);
    conv_mfma<<<dim3(512), dim3(256), 0, stream>>>(xT, wT2, bias, out, tmpb, part);
    bn_stats_prelu_b<<<dim3(2048), dim3(256), 0, stream>>>(part, gamma, beta, alpha, tmpb, out);
  } else if (ws_size >= WS_NEED) {
    prep_kernel<<<dim3(1176), dim3(256), 0, stream>>>(x, w, xT, wT2);
    conv_mfma<<<dim3(512), dim3(256), 0, stream>>>(xT, wT2, bias, out, nullptr, part);
    bn_stats_prelu_f<<<dim3(2048), dim3(256), 0, stream>>>(part, gamma, beta, alpha, out);
  }
}

// Round 17
// 51.644 us; speedup vs baseline: 1.0416x; 1.0416x over previous
//
#include <hip/hip_runtime.h>

typedef __attribute__((ext_vector_type(8))) short short8;
typedef __attribute__((ext_vector_type(8))) unsigned short ushort8;
typedef __attribute__((ext_vector_type(4))) float f32x4;

// Problem constants
constexpr int B_ = 8, IN_C_ = 64, IN_L_ = 64, T_ = 256, OUT_C_ = 64, OUT_L_ = 64;
constexpr float EPS_ = 1e-5f;

// xT_pad: bf16 [8 b][66 lp][258 tp][64 ic]; lp = l+1, tp = t+1, halo rows/cols = 0
constexpr int XT_LP = 66, XT_TP = 258, XT_IC = 64;
constexpr int XT_LSTRIDE = XT_TP * XT_IC;            // 16512 elems
constexpr int XT_BSTRIDE = XT_LP * XT_LSTRIDE;       // 1,089,792 elems
constexpr size_t XT_ELEMS = (size_t)B_ * XT_BSTRIDE; // 8,718,336
constexpr size_t XT_BYTES = XT_ELEMS * 2;            // 17,436,672
// wT2: bf16 [64 l][9 tap][64 c][64 ic]
constexpr size_t WT2_ELEMS = 64ull * 9 * 64 * 64;    // 2,359,296
constexpr size_t WT2_OFF_B = XT_BYTES;
constexpr size_t PART_OFF_B = WT2_OFF_B + WT2_ELEMS * 2;   // 22,155,264
constexpr size_t PART_BYTES = 512ull * 128 * 4;            // 256 KB
constexpr size_t TMP_OFF_B = PART_OFF_B + PART_BYTES;      // 22,417,408
constexpr size_t TMP_BYTES = (size_t)B_ * OUT_C_ * OUT_L_ * T_ * 2;
constexpr size_t WS_NEED = TMP_OFF_B;                      // fp32 fallback
constexpr size_t WS_NEED2 = TMP_OFF_B + TMP_BYTES;         // 39,194,624

__device__ __forceinline__ unsigned short f2bf(float f) {
  unsigned u = __float_as_uint(f);
  return (unsigned short)((u + 0x7fffu + ((u >> 16) & 1u)) >> 16);
}

__device__ __forceinline__ void gload_lds16(const void* g, void* l) {
  __builtin_amdgcn_global_load_lds(
      (const __attribute__((address_space(1))) unsigned int*)g,
      (__attribute__((address_space(3))) unsigned int*)l, 16, 0, 0);
}

// ---------------------------------------------------------------------------
// Prep (r12): blocks [0,144) coalesced wprep transpose;
// [144,1168) xprep LDS transpose; [1168,1176) xT halo zero.
// ---------------------------------------------------------------------------
__global__ __launch_bounds__(256) void prep_kernel(const float* __restrict__ x,
                                                   const float* __restrict__ w,
                                                   unsigned short* __restrict__ xT,
                                                   unsigned short* __restrict__ wT2) {
  const int bid = blockIdx.x;
  const int tid = threadIdx.x;
  __shared__ unsigned char shmem[34816];
  if (bid < 144) {
    const int tap = bid >> 4;
    const int c0 = (bid & 15) * 4;
    auto wls = (unsigned short(*)[4][68])shmem;  // [l][cl][ic] (pad 68)
    {
      const int ic = tid >> 2, cl = tid & 3;
      const float* src = w + (((size_t)(ic * 9 + tap) * 64) + (c0 + cl)) * 64;
#pragma unroll
      for (int e = 0; e < 16; ++e) {
        float4 v = ((const float4*)src)[e];
        const int l = e * 4;
        wls[l + 0][cl][ic] = f2bf(v.x);
        wls[l + 1][cl][ic] = f2bf(v.y);
        wls[l + 2][cl][ic] = f2bf(v.z);
        wls[l + 3][cl][ic] = f2bf(v.w);
      }
    }
    __syncthreads();
    {
      const int l = tid >> 2, cl = tid & 3;
      const unsigned short* row = &wls[l][cl][0];
      uint4* dst = (uint4*)(wT2 + ((size_t)(l * 9 + tap)) * 4096 + (c0 + cl) * 64);
#pragma unroll
      for (int q = 0; q < 8; ++q) dst[q] = ((const uint4*)row)[q];
    }
  } else if (bid < 1168) {
    const int u = bid - 144;
    const int th = u & 1, l = (u >> 1) & 63, b = u >> 7;
    const int t0 = th * 128;
    auto ls = (unsigned short(*)[132])shmem;  // [ic][t-local]
    {
      const int ic = tid >> 2, q = tid & 3;
      const float4* src = (const float4*)(x + (((size_t)(b * 64 + ic) * 64 + l) * 256 + t0));
#pragma unroll
      for (int e = 0; e < 8; ++e) {
        float4 v = src[q * 8 + e];
        const int toff = (q * 8 + e) * 4;
        unsigned d0 = f2bf(v.x) | ((unsigned)f2bf(v.y) << 16);
        unsigned d1 = f2bf(v.z) | ((unsigned)f2bf(v.w) << 16);
        *(uint2*)&ls[ic][toff] = make_uint2(d0, d1);
      }
    }
    __syncthreads();
    {
      const int tl = tid >> 1, h = tid & 1;  // t-row, ic-half
      unsigned d[16];
#pragma unroll
      for (int k = 0; k < 16; ++k) {
        unsigned short a = ls[h * 32 + 2 * k][tl];
        unsigned short c = ls[h * 32 + 2 * k + 1][tl];
        d[k] = a | ((unsigned)c << 16);
      }
      unsigned short* dst =
          xT + ((size_t)(b * XT_LP + l + 1) * XT_TP + (t0 + tl + 1)) * XT_IC + h * 32;
      uint4* dv = (uint4*)dst;
      dv[0] = make_uint4(d[0], d[1], d[2], d[3]);
      dv[1] = make_uint4(d[4], d[5], d[6], d[7]);
      dv[2] = make_uint4(d[8], d[9], d[10], d[11]);
      dv[3] = make_uint4(d[12], d[13], d[14], d[15]);
    }
  } else {
    const int b = bid - 1168;  // 0..7
    unsigned short* base = xT + (size_t)b * XT_BSTRIDE;
    const short8 z = {};
    for (int ci = tid; ci < 5184; ci += 256) {
      size_t off;
      if (ci < 4128) {
        const int plane = ci / 2064, k = ci % 2064;
        off = (size_t)(plane ? 65 : 0) * XT_LSTRIDE + (size_t)k * 8;
      } else {
        const int k = ci - 4128;
        const int lp = k >> 4, rem = k & 15;
        const int tp = (rem < 8) ? 0 : 257;
        off = ((size_t)lp * XT_TP + tp) * 64 + (size_t)(rem & 7) * 8;
      }
      *(short8*)(base + off) = z;
    }
  }
}

// ---------------------------------------------------------------------------
// Main conv (r15, best measured): per (b,l) block, 256x64 GEMM over K=576 =
// 3 rows x 3 col-shifts x 64. A = one full padded xT row (258x64, 36 KB incl.
// unguarded overrun pad) staged per i-row — taps j=0..2 read it at column
// offset t+j (A staged 3x instead of 9x). B = 8 KB LDS double-buffer with
// counted vmcnt(2) (in-order vmcnt retirement drains B(tap) + any row-A
// loads). 4 waves x 64t x 64c, acc 4x4. XOR-swizzled LDS via pre-swizzled
// global source. l-major XCD swizzle (per-XCD set ~3.2 MB, L2-resident).
// ---------------------------------------------------------------------------
__global__ __launch_bounds__(256, 2) void conv_mfma(
    const unsigned short* __restrict__ xT, const unsigned short* __restrict__ wT2,
    const float* __restrict__ bias, float* __restrict__ outf,
    unsigned short* __restrict__ tmpb, float* __restrict__ part) {
  const int orig = blockIdx.x;  // 0..511
  // l-major XCD swizzle: b = orig>>6, l = (orig&7)*8 + ((orig>>3)&7)
  const int wg = (orig >> 6) * 64 + (orig & 7) * 8 + ((orig >> 3) & 7);
  const int b = wg >> 6, l = wg & 63;
  const int tid = threadIdx.x;
  const int wid = tid >> 6, ln = tid & 63;
  const int lc = ln & 15, lg = ln >> 4;
  const int m0 = wid * 64;

  __shared__ unsigned short Arow[18432];   // 36 KB: one xT row (16512) + pad
  __shared__ unsigned short Bl[2][4096];   // 16 KB: B double buffer

  // B source pre-swizzle (r12 pattern): dst slot ln&7 of row-sub ln>>3 takes
  // global slot (ln&7)^(ln>>3)
  const int src_lane_off = ((ln >> 3) << 6) + ((((ln & 7) ^ (ln >> 3))) << 3);
  const unsigned short* wBase = wT2 + (size_t)l * 9 * 4096 + src_lane_off;
  const unsigned short* xRow0 = xT + (size_t)(b * XT_LP + l) * XT_LSTRIDE;

  // A row stage: 2304 chunks (2064 real + unguarded overrun pad; pad reads
  // land in later xT rows — in-bounds of ws, never consumed).
  // Chunk ci: tp=ci>>3, slot s=ci&7; LDS slot s holds global slot s^(tp&7).
  auto ASTAGE = [&](int i) {
    const unsigned short* rb = xRow0 + (size_t)i * XT_LSTRIDE;
#pragma unroll
    for (int k = 0; k < 9; ++k) {
      const int cbase = k * 256 + wid * 64;  // wave-uniform
      const int ci = cbase + ln;
      const int tp = ci >> 3, s = ci & 7;
      gload_lds16(rb + tp * 64 + ((s ^ (tp & 7)) << 3), Arow + (size_t)cbase * 8);
    }
  };
  auto BSTAGE = [&](int buf, int tap) {
    const unsigned short* Bb = wBase + (size_t)tap * 4096;
#pragma unroll
    for (int q = 0; q < 2; ++q) {
      const int ch = wid * 2 + q;
      gload_lds16(Bb + ch * 512, &Bl[buf][0] + ch * 512);
    }
  };

  f32x4 acc[4][4] = {};

  ASTAGE(0);
  BSTAGE(0, 0);
  __syncthreads();  // prologue full drain: A row 0 + B(0) landed & visible

#pragma unroll
  for (int tap = 0; tap < 9; ++tap) {
    const int i = tap / 3, j = tap - i * 3;  // compile-time (unrolled)
    // barrier 1: all waves finished reading Bl[(tap+1)&1] (used at tap-1)
    __builtin_amdgcn_s_barrier();
    if (tap + 1 < 9) {
      BSTAGE((tap + 1) & 1, tap + 1);  // 2 gloads/wave, youngest outstanding
      asm volatile("s_waitcnt vmcnt(2)" ::: "memory");  // B(tap)+A(row) landed
    } else {
      asm volatile("s_waitcnt vmcnt(0)" ::: "memory");
    }
    __builtin_amdgcn_sched_barrier(0);
    // barrier 2: every wave's staging contributions now visible
    __builtin_amdgcn_s_barrier();
    __builtin_amdgcn_sched_barrier(0);

    const unsigned short* Lb = &Bl[tap & 1][0];
#pragma unroll
    for (int kb = 0; kb < 2; ++kb) {
      const int q = kb * 4 + lg;
      short8 af[4], bf[4];
#pragma unroll
      for (int mi = 0; mi < 4; ++mi) {
        const int tp = m0 + mi * 16 + lc + j;  // column t+j, <= 257
        af[mi] = *(const short8*)(Arow + tp * 64 + ((q ^ (tp & 7)) << 3));
      }
#pragma unroll
      for (int ni = 0; ni < 4; ++ni)
        bf[ni] = *(const short8*)(Lb + (ni * 16 + lc) * 64 + ((q ^ (lc & 7)) << 3));
#pragma unroll
      for (int mi = 0; mi < 4; ++mi)
#pragma unroll
        for (int ni = 0; ni < 4; ++ni)
          acc[mi][ni] =
              __builtin_amdgcn_mfma_f32_16x16x32_bf16(af[mi], bf[ni], acc[mi][ni], 0, 0, 0);
    }

    if (j == 2 && i < 2) {
      __builtin_amdgcn_s_barrier();  // all waves done reading Arow(i)
      ASTAGE(i + 1);                 // drained by next tap's vmcnt(2)+barrier
    }
  }

  // epilogue: bias + store (bf16 or fp32) + fused stats.
  __syncthreads();
  float* sm = (float*)&Arow[0];  // sm[(wid*4+ni)*32 + lc*2 + sel]
#pragma unroll
  for (int ni = 0; ni < 4; ++ni) {
    const int c = ni * 16 + lc;
    const float bv = bias[c * 64 + l];
    float s = 0.f, s2 = 0.f;
    const size_t obase = ((size_t)(b * 64 + c) * 64 + l) * 256 + m0;
#pragma unroll
    for (int mi = 0; mi < 4; ++mi) {
      float vv[4];
#pragma unroll
      for (int r = 0; r < 4; ++r) {
        float v = acc[mi][ni][r] + bv;
        vv[r] = v;
        s += v;
        s2 += v * v;
      }
      if (tmpb) {
        unsigned d0 = f2bf(vv[0]) | ((unsigned)f2bf(vv[1]) << 16);
        unsigned d1 = f2bf(vv[2]) | ((unsigned)f2bf(vv[3]) << 16);
        *(uint2*)(tmpb + obase + mi * 16 + lg * 4) = make_uint2(d0, d1);
      } else {
        *(float4*)(outf + obase + mi * 16 + lg * 4) =
            make_float4(vv[0], vv[1], vv[2], vv[3]);
      }
    }
    s += __shfl_xor(s, 16);  s += __shfl_xor(s, 32);
    s2 += __shfl_xor(s2, 16); s2 += __shfl_xor(s2, 32);
    if (lg == 0) {
      sm[(wid * 4 + ni) * 32 + lc * 2] = s;
      sm[(wid * 4 + ni) * 32 + lc * 2 + 1] = s2;
    }
  }
  __syncthreads();
  if (tid < 128) {
    const int sel = tid >> 6, cc = tid & 63;
    const int ni = cc >> 4, lc2 = cc & 15;
    float r = 0.f;
#pragma unroll
    for (int w2 = 0; w2 < 4; ++w2) r += sm[(w2 * 4 + ni) * 32 + lc2 * 2 + sel];
    part[(size_t)wg * 128 + sel * 64 + cc] = r;
  }
}

// ---------------------------------------------------------------------------
// Merged stats + BN + PReLU (bf16 tmp -> fp32 out). Block = (c, seg):
// phase 1: redundantly reduce the 512x2 per-block partials for channel c;
// phase 2: apply BN+PReLU to a 1/32 slice of channel c.
// ---------------------------------------------------------------------------
__global__ __launch_bounds__(256) void bn_stats_prelu_b(
    const float* __restrict__ part, const float* __restrict__ gamma,
    const float* __restrict__ beta, const float* __restrict__ alpha,
    const unsigned short* __restrict__ tmp, float* __restrict__ out) {
  const int c = blockIdx.x >> 5;
  const int seg = blockIdx.x & 31;
  const int tid = threadIdx.x;
  float s = 0.f, s2 = 0.f;
  for (int i = tid; i < 512; i += 256) {
    s += part[(size_t)i * 128 + c];
    s2 += part[(size_t)i * 128 + 64 + c];
  }
#pragma unroll
  for (int off = 32; off; off >>= 1) {
    s += __shfl_down(s, off);
    s2 += __shfl_down(s2, off);
  }
  __shared__ float r0[4], r1[4];
  const int wid = tid >> 6, lane = tid & 63;
  if (lane == 0) { r0[wid] = s; r1[wid] = s2; }
  __syncthreads();
  const float S = r0[0] + r0[1] + r0[2] + r0[3];
  const float S2 = r1[0] + r1[1] + r1[2] + r1[3];
  const float inv_n = 1.0f / 131072.f;
  const float mean = S * inv_n;
  const float var = S2 * inv_n - mean * mean;
  const float sc = gamma[c] * rsqrtf(var + EPS_);
  const float sh = beta[c] - mean * sc;
  const float a = alpha[0];
  // slice: b = seg>>2, quarter = seg&3 ; per (b,c) plane = 2048 ushort8 chunks
  const size_t base8 = ((size_t)((seg >> 2) * 64 + c)) * 2048 + (size_t)(seg & 3) * 512;
#pragma unroll 2
  for (int k = tid; k < 512; k += 256) {
    const size_t i = base8 + k;
    ushort8 v = *(const ushort8*)(tmp + i * 8);
    float o[8];
#pragma unroll
    for (int r = 0; r < 8; ++r) {
      float f = __uint_as_float(((unsigned)v[r]) << 16) * sc + sh;
      o[r] = (f >= 0.f) ? f : a * f;
    }
    float4* op = (float4*)(out + i * 8);
    op[0] = make_float4(o[0], o[1], o[2], o[3]);
    op[1] = make_float4(o[4], o[5], o[6], o[7]);
  }
}

// fp32-in-place fallback variant (no tmp buffer).
__global__ __launch_bounds__(256) void bn_stats_prelu_f(
    const float* __restrict__ part, const float* __restrict__ gamma,
    const float* __restrict__ beta, const float* __restrict__ alpha,
    float* __restrict__ out) {
  const int c = blockIdx.x >> 5;
  const int seg = blockIdx.x & 31;
  const int tid = threadIdx.x;
  float s = 0.f, s2 = 0.f;
  for (int i = tid; i < 512; i += 256) {
    s += part[(size_t)i * 128 + c];
    s2 += part[(size_t)i * 128 + 64 + c];
  }
#pragma unroll
  for (int off = 32; off; off >>= 1) {
    s += __shfl_down(s, off);
    s2 += __shfl_down(s2, off);
  }
  __shared__ float r0[4], r1[4];
  const int wid = tid >> 6, lane = tid & 63;
  if (lane == 0) { r0[wid] = s; r1[wid] = s2; }
  __syncthreads();
  const float S = r0[0] + r0[1] + r0[2] + r0[3];
  const float S2 = r1[0] + r1[1] + r1[2] + r1[3];
  const float inv_n = 1.0f / 131072.f;
  const float mean = S * inv_n;
  const float var = S2 * inv_n - mean * mean;
  const float sc = gamma[c] * rsqrtf(var + EPS_);
  const float sh = beta[c] - mean * sc;
  const float a = alpha[0];
  const size_t base4 = ((size_t)((seg >> 2) * 64 + c)) * 4096 + (size_t)(seg & 3) * 1024;
  for (int k = tid; k < 1024; k += 256) {
    float4 v = ((float4*)out)[base4 + k];
    v.x = v.x * sc + sh; v.x = (v.x >= 0.f) ? v.x : a * v.x;
    v.y = v.y * sc + sh; v.y = (v.y >= 0.f) ? v.y : a * v.y;
    v.z = v.z * sc + sh; v.z = (v.z >= 0.f) ? v.z : a * v.z;
    v.w = v.w * sc + sh; v.w = (v.w >= 0.f) ? v.w : a * v.w;
    ((float4*)out)[base4 + k] = v;
  }
}

extern "C" void kernel_launch(void* const* d_in, const int* in_sizes, int n_in,
                              void* d_out, int out_size, void* d_ws, size_t ws_size,
                              hipStream_t stream) {
  const float* x = (const float*)d_in[0];
  const float* w = (const float*)d_in[1];
  const float* bias = (const float*)d_in[2];
  const float* gamma = (const float*)d_in[3];
  const float* beta = (const float*)d_in[4];
  const float* alpha = (const float*)d_in[5];
  float* out = (float*)d_out;

  unsigned short* xT = (unsigned short*)d_ws;
  unsigned short* wT2 = (unsigned short*)((char*)d_ws + WT2_OFF_B);
  float* part = (float*)((char*)d_ws + PART_OFF_B);

  if (ws_size >= WS_NEED2) {
    unsigned short* tmpb = (unsigned short*)((char*)d_ws + TMP_OFF_B);
    prep_kernel<<<dim3(1176), dim3(256), 0, stream>>>(x, w, xT, wT2);
    conv_mfma<<<dim3(512), dim3(256), 0, stream>>>(xT, wT2, bias, out, tmpb, part);
    bn_stats_prelu_b<<<dim3(2048), dim3(256), 0, stream>>>(part, gamma, beta, alpha, tmpb, out);
  } else if (ws_size >= WS_NEED) {
    prep_kernel<<<dim3(1176), dim3(256), 0, stream>>>(x, w, xT, wT2);
    conv_mfma<<<dim3(512), dim3(256), 0, stream>>>(xT, wT2, bias, out, nullptr, part);
    bn_stats_prelu_f<<<dim3(2048), dim3(256), 0, stream>>>(part, gamma, beta, alpha, out);
  }
}